// Round 4
// baseline (68.757 us; speedup 1.0000x reference)
//
#include <hip/hip_runtime.h>

// Fused anisotropic upsampling:
//   out0 = (up_h(x0) + up_w(x1)) / 2 : (N,128,256), N = 8*64 = 512
//   out1 = (up_h(x1) + up_w(x2)) / 2 : (N,256,128)
// Upsample closed form (L=5, s=2), output length 2W from input length W:
//   j odd , j<=2W-3 : (x[(j-1)/2] + x[(j+1)/2]) / 2
//   j even interior : (x[j/2-1] + x[j/2] + x[j/2+1]) / 3
//   j==0            : (x[0] + x[1]) / 2
//   j==2W-2         : (x[W-2] + x[W-1]) / 2
//   j==2W-1         : x[W-1]
//
// Thread tile: 4 output rows (4hb..4hb+3) x 8 cols (8t..8t+7).
//   a rows loaded: 2hb-1 (halo), 2hb, 2hb+1, 2hb+2 (halo) -> 8 float4
//   b rows loaded: 4 x float4; w-halo comes from lane shuffles (boundary
//   lanes land on first/last cases where the halo operand is unselected).

typedef float vfloat4 __attribute__((ext_vector_type(4)));

__device__ __forceinline__ float4 f4_add(float4 p, float4 q) {
    return make_float4(p.x + q.x, p.y + q.y, p.z + q.z, p.w + q.w);
}
__device__ __forceinline__ float4 f4_scale(float4 p, float s) {
    return make_float4(p.x * s, p.y * s, p.z * s, p.w * s);
}

// up_w of one b-row segment: b[4t-1..4t+4] -> outputs w=8t..8t+7 (two float4)
__device__ __forceinline__ void upw8(float bm, float4 bq, float bp,
                                     bool first, bool last,
                                     float4& lo, float4& hi) {
    constexpr float THIRD = 1.0f / 3.0f;
    lo.x = first ? 0.5f * (bq.x + bq.y) : (bm + bq.x + bq.y) * THIRD;
    lo.y = 0.5f * (bq.x + bq.y);
    lo.z = (bq.x + bq.y + bq.z) * THIRD;
    lo.w = 0.5f * (bq.y + bq.z);
    hi.x = (bq.y + bq.z + bq.w) * THIRD;
    hi.y = 0.5f * (bq.z + bq.w);
    hi.z = last ? 0.5f * (bq.z + bq.w) : (bq.z + bq.w + bp) * THIRD;
    hi.w = last ? bq.w : 0.5f * (bq.w + bp);
}

__device__ __forceinline__ void store_nt(float4* p, float4 v) {
    vfloat4 vv;
    vv.x = v.x; vv.y = v.y; vv.z = v.z; vv.w = v.w;
    __builtin_nontemporal_store(vv, reinterpret_cast<vfloat4*>(p));
}

template <int Ha, int Wo>
__device__ __forceinline__ void up_combine_body(
    const float* __restrict__ a,   // (N, Ha, Wo)
    const float* __restrict__ b,   // (N, 2*Ha, Wo/2)
    float* __restrict__ out,       // (N, 2*Ha, Wo)
    int lin)
{
    constexpr int H2 = 2 * Ha;
    constexpr int HB = Ha / 2;     // 4-output-row blocks
    constexpr int Wb = Wo / 2;
    constexpr int W4 = Wo / 4;     // float4 per output row
    constexpr int T8 = Wo / 8;     // 8-wide groups per output row
    constexpr float THIRD = 1.0f / 3.0f;

    const int t  = lin % T8;
    const int hb = (lin / T8) % HB;
    const int n  = lin / (T8 * HB);

    // ---------------- a rows: 2hb-1, 2hb, 2hb+1, 2hb+2 ----------------
    const float4* a4 = reinterpret_cast<const float4*>(a)
                     + (size_t)n * Ha * W4 + (size_t)(2 * hb) * W4 + 2 * t;
    const bool htop = (hb == 0), hbot = (hb == HB - 1);
    float4 a0l = a4[0],  a0h = a4[1];          // row 2hb
    float4 a1l = a4[W4], a1h = a4[W4 + 1];     // row 2hb+1
    float4 aml, amh, apl, aph;
    if (!htop) { aml = a4[-W4];     amh = a4[-W4 + 1]; }
    if (!hbot) { apl = a4[2 * W4];  aph = a4[2 * W4 + 1]; }

    // up_h for output rows 4hb..4hb+3 (low/high float4 each)
    float4 h0l, h0h, h1l, h1h, h2l, h2h, h3l, h3h;
    float4 s01l = f4_add(a0l, a1l), s01h = f4_add(a0h, a1h);
    h0l = htop ? f4_scale(s01l, 0.5f) : f4_scale(f4_add(aml, s01l), THIRD);
    h0h = htop ? f4_scale(s01h, 0.5f) : f4_scale(f4_add(amh, s01h), THIRD);
    h1l = f4_scale(s01l, 0.5f);
    h1h = f4_scale(s01h, 0.5f);
    h2l = hbot ? f4_scale(s01l, 0.5f) : f4_scale(f4_add(s01l, apl), THIRD);
    h2h = hbot ? f4_scale(s01h, 0.5f) : f4_scale(f4_add(s01h, aph), THIRD);
    h3l = hbot ? a1l : f4_scale(f4_add(a1l, apl), 0.5f);
    h3h = hbot ? a1h : f4_scale(f4_add(a1h, aph), 0.5f);

    // ---------------- b rows: 4hb .. 4hb+3 ----------------
    const bool first = (t == 0), last = (t == T8 - 1);
    const float* brow = b + ((size_t)n * H2 + (size_t)(4 * hb)) * Wb + 4 * t;
    float4 bq0 = *reinterpret_cast<const float4*>(brow);
    float4 bq1 = *reinterpret_cast<const float4*>(brow + Wb);
    float4 bq2 = *reinterpret_cast<const float4*>(brow + 2 * Wb);
    float4 bq3 = *reinterpret_cast<const float4*>(brow + 3 * Wb);

    // halo via lane shuffles (row-group boundaries hit first/last cases
    // where the shuffled value is unselected)
    float bm0 = __shfl_up(bq0.w, 1), bp0 = __shfl_down(bq0.x, 1);
    float bm1 = __shfl_up(bq1.w, 1), bp1 = __shfl_down(bq1.x, 1);
    float bm2 = __shfl_up(bq2.w, 1), bp2 = __shfl_down(bq2.x, 1);
    float bm3 = __shfl_up(bq3.w, 1), bp3 = __shfl_down(bq3.x, 1);

    float4 w0l, w0h, w1l, w1h, w2l, w2h, w3l, w3h;
    upw8(bm0, bq0, bp0, first, last, w0l, w0h);
    upw8(bm1, bq1, bp1, first, last, w1l, w1h);
    upw8(bm2, bq2, bp2, first, last, w2l, w2h);
    upw8(bm3, bq3, bp3, first, last, w3l, w3h);

    // ---------------- combine & store (nontemporal) ----------------
    float4* o4 = reinterpret_cast<float4*>(out)
               + ((size_t)n * H2 + (size_t)(4 * hb)) * W4 + 2 * t;
    store_nt(o4 + 0,          f4_scale(f4_add(h0l, w0l), 0.5f));
    store_nt(o4 + 1,          f4_scale(f4_add(h0h, w0h), 0.5f));
    store_nt(o4 + W4,         f4_scale(f4_add(h1l, w1l), 0.5f));
    store_nt(o4 + W4 + 1,     f4_scale(f4_add(h1h, w1h), 0.5f));
    store_nt(o4 + 2 * W4,     f4_scale(f4_add(h2l, w2l), 0.5f));
    store_nt(o4 + 2 * W4 + 1, f4_scale(f4_add(h2h, w2h), 0.5f));
    store_nt(o4 + 3 * W4,     f4_scale(f4_add(h3l, w3l), 0.5f));
    store_nt(o4 + 3 * W4 + 1, f4_scale(f4_add(h3h, w3h), 0.5f));
}

__global__ __launch_bounds__(256) void fused_up_kernel(
    const float* __restrict__ x0,
    const float* __restrict__ x1,
    const float* __restrict__ x2,
    float* __restrict__ out0,
    float* __restrict__ out1,
    int g0_blocks)
{
    if (blockIdx.x < (unsigned)g0_blocks) {
        const int lin = blockIdx.x * blockDim.x + threadIdx.x;
        up_combine_body<64, 256>(x0, x1, out0, lin);
    } else {
        const int lin = (blockIdx.x - g0_blocks) * blockDim.x + threadIdx.x;
        up_combine_body<128, 128>(x1, x2, out1, lin);
    }
}

extern "C" void kernel_launch(void* const* d_in, const int* in_sizes, int n_in,
                              void* d_out, int out_size, void* d_ws, size_t ws_size,
                              hipStream_t stream) {
    const float* x0 = (const float*)d_in[0];  // (8,64, 64,256)
    const float* x1 = (const float*)d_in[1];  // (8,64,128,128)
    const float* x2 = (const float*)d_in[2];  // (8,64,256, 64)
    float* out = (float*)d_out;

    const int N = 8 * 64;  // 512
    float* out0 = out;
    float* out1 = out + (size_t)N * 128 * 256;

    // Segment 0: 512 * 32 hb * 32 t = 524288 threads -> 2048 blocks
    // Segment 1: 512 * 64 hb * 16 t = 524288 threads -> 2048 blocks
    const int g0 = (N * (64 / 2) * (256 / 8)) / 256;
    const int g1 = (N * (128 / 2) * (128 / 8)) / 256;
    dim3 grid(g0 + g1), block(256);
    hipLaunchKernelGGL(fused_up_kernel, grid, block, 0, stream,
                       x0, x1, x2, out0, out1, g0);
}

// Round 5
// 45.142 us; speedup vs baseline: 1.5231x; 1.5231x over previous
//
#include <hip/hip_runtime.h>

// Fused anisotropic upsampling:
//   out0 = (up_h(x0) + up_w(x1)) / 2 : (N,128,256), N = 8*64 = 512
//   out1 = (up_h(x1) + up_w(x2)) / 2 : (N,256,128)
// Upsample closed form (L=5, s=2), output length 2W from input length W:
//   j odd , j<=2W-3 : (x[(j-1)/2] + x[(j+1)/2]) / 2
//   j even interior : (x[j/2-1] + x[j/2] + x[j/2+1]) / 3
//   j==0            : (x[0] + x[1]) / 2
//   j==2W-2         : (x[W-2] + x[W-1]) / 2
//   j==2W-1         : x[W-1]
//
// Thread tile: 4 output rows (4hb..4hb+3) x 4 cols (4t..4t+3).
// All loads and stores are wave-contiguous per instruction:
//   stores: 4x float4, lane stride 16 B -> 1 KiB/wave full lines
//   a loads: 4x float4 (rows 2hb-1..2hb+2), lane stride 16 B
//   b loads: 4x float2 (rows 4hb..4hb+3), lane stride 8 B
// b w-halo via lane shuffles; boundary lanes hit first/last predicates
// where the shuffled operand is unselected.

__device__ __forceinline__ float4 f4_add(float4 p, float4 q) {
    return make_float4(p.x + q.x, p.y + q.y, p.z + q.z, p.w + q.w);
}
__device__ __forceinline__ float4 f4_scale(float4 p, float s) {
    return make_float4(p.x * s, p.y * s, p.z * s, p.w * s);
}

// up_w of one b-row pair: b[2t-1..2t+2] -> outputs w=4t..4t+3
__device__ __forceinline__ float4 upw4(float bm, float2 bq, float bp,
                                       bool first, bool last) {
    constexpr float THIRD = 1.0f / 3.0f;
    float4 r;
    r.x = first ? 0.5f * (bq.x + bq.y) : (bm + bq.x + bq.y) * THIRD;
    r.y = 0.5f * (bq.x + bq.y);
    r.z = last ? 0.5f * (bq.x + bq.y) : (bq.x + bq.y + bp) * THIRD;
    r.w = last ? bq.y : 0.5f * (bq.y + bp);
    return r;
}

template <int Ha, int Wo>
__device__ __forceinline__ void up_combine_body(
    const float* __restrict__ a,   // (N, Ha, Wo)
    const float* __restrict__ b,   // (N, 2*Ha, Wo/2)
    float* __restrict__ out,       // (N, 2*Ha, Wo)
    int lin)
{
    constexpr int H2 = 2 * Ha;
    constexpr int HB = Ha / 2;     // 4-output-row blocks
    constexpr int Wb = Wo / 2;
    constexpr int W4 = Wo / 4;     // float4 per output row
    constexpr int T4 = Wo / 4;     // 4-wide groups per output row
    constexpr float THIRD = 1.0f / 3.0f;

    const int t  = lin % T4;
    const int hb = (lin / T4) % HB;
    const int n  = lin / (T4 * HB);

    // ---------------- a rows: 2hb-1, 2hb, 2hb+1, 2hb+2 (col 4t) ----------
    const float4* a4 = reinterpret_cast<const float4*>(a)
                     + (size_t)n * Ha * W4 + (size_t)(2 * hb) * W4 + t;
    const bool htop = (hb == 0), hbot = (hb == HB - 1);
    float4 a0 = a4[0];            // row 2hb
    float4 a1 = a4[W4];           // row 2hb+1
    float4 am, ap;
    if (!htop) am = a4[-W4];
    if (!hbot) ap = a4[2 * W4];

    // up_h for output rows 4hb..4hb+3
    float4 s01 = f4_add(a0, a1);
    float4 h0 = htop ? f4_scale(s01, 0.5f) : f4_scale(f4_add(am, s01), THIRD);
    float4 h1 = f4_scale(s01, 0.5f);
    float4 h2 = hbot ? f4_scale(s01, 0.5f) : f4_scale(f4_add(s01, ap), THIRD);
    float4 h3 = hbot ? a1 : f4_scale(f4_add(a1, ap), 0.5f);

    // ---------------- b rows: 4hb .. 4hb+3 (cols 2t, 2t+1) ---------------
    const bool first = (t == 0), last = (t == T4 - 1);
    const float* brow = b + ((size_t)n * H2 + (size_t)(4 * hb)) * Wb + 2 * t;
    float2 bq0 = *reinterpret_cast<const float2*>(brow);
    float2 bq1 = *reinterpret_cast<const float2*>(brow + Wb);
    float2 bq2 = *reinterpret_cast<const float2*>(brow + 2 * Wb);
    float2 bq3 = *reinterpret_cast<const float2*>(brow + 3 * Wb);

    float bm0 = __shfl_up(bq0.y, 1), bp0 = __shfl_down(bq0.x, 1);
    float bm1 = __shfl_up(bq1.y, 1), bp1 = __shfl_down(bq1.x, 1);
    float bm2 = __shfl_up(bq2.y, 1), bp2 = __shfl_down(bq2.x, 1);
    float bm3 = __shfl_up(bq3.y, 1), bp3 = __shfl_down(bq3.x, 1);

    float4 w0 = upw4(bm0, bq0, bp0, first, last);
    float4 w1 = upw4(bm1, bq1, bp1, first, last);
    float4 w2 = upw4(bm2, bq2, bp2, first, last);
    float4 w3 = upw4(bm3, bq3, bp3, first, last);

    // ---------------- combine & store (wave-contiguous float4) -----------
    float4* o4 = reinterpret_cast<float4*>(out)
               + ((size_t)n * H2 + (size_t)(4 * hb)) * W4 + t;
    o4[0]      = f4_scale(f4_add(h0, w0), 0.5f);
    o4[W4]     = f4_scale(f4_add(h1, w1), 0.5f);
    o4[2 * W4] = f4_scale(f4_add(h2, w2), 0.5f);
    o4[3 * W4] = f4_scale(f4_add(h3, w3), 0.5f);
}

__global__ __launch_bounds__(256) void fused_up_kernel(
    const float* __restrict__ x0,
    const float* __restrict__ x1,
    const float* __restrict__ x2,
    float* __restrict__ out0,
    float* __restrict__ out1,
    int g0_blocks)
{
    if (blockIdx.x < (unsigned)g0_blocks) {
        const int lin = blockIdx.x * blockDim.x + threadIdx.x;
        up_combine_body<64, 256>(x0, x1, out0, lin);
    } else {
        const int lin = (blockIdx.x - g0_blocks) * blockDim.x + threadIdx.x;
        up_combine_body<128, 128>(x1, x2, out1, lin);
    }
}

extern "C" void kernel_launch(void* const* d_in, const int* in_sizes, int n_in,
                              void* d_out, int out_size, void* d_ws, size_t ws_size,
                              hipStream_t stream) {
    const float* x0 = (const float*)d_in[0];  // (8,64, 64,256)
    const float* x1 = (const float*)d_in[1];  // (8,64,128,128)
    const float* x2 = (const float*)d_in[2];  // (8,64,256, 64)
    float* out = (float*)d_out;

    const int N = 8 * 64;  // 512
    float* out0 = out;
    float* out1 = out + (size_t)N * 128 * 256;

    // Segment 0: 512 * 32 hb * 64 t = 1,048,576 threads -> 4096 blocks
    // Segment 1: 512 * 64 hb * 32 t = 1,048,576 threads -> 4096 blocks
    const int g0 = (N * (64 / 2) * (256 / 4)) / 256;
    const int g1 = (N * (128 / 2) * (128 / 4)) / 256;
    dim3 grid(g0 + g1), block(256);
    hipLaunchKernelGGL(fused_up_kernel, grid, block, 0, stream,
                       x0, x1, x2, out0, out1, g0);
}

// Round 6
// 44.864 us; speedup vs baseline: 1.5325x; 1.0062x over previous
//
#include <hip/hip_runtime.h>

// Fused anisotropic upsampling:
//   out0 = (up_h(x0) + up_w(x1)) / 2 : (N,128,256), N = 8*64 = 512
//   out1 = (up_h(x1) + up_w(x2)) / 2 : (N,256,128)
// Upsample closed form (L=5, s=2), output length 2W from input length W:
//   j odd , j<=2W-3 : (x[(j-1)/2] + x[(j+1)/2]) / 2
//   j even interior : (x[j/2-1] + x[j/2] + x[j/2+1]) / 3
//   j==0            : (x[0] + x[1]) / 2
//   j==2W-2         : (x[W-2] + x[W-1]) / 2
//   j==2W-1         : x[W-1]
//
// Thread tile: 4 output rows (4hb..4hb+3) x 4 cols (4t..4t+3).
// All loads and stores are wave-contiguous per instruction:
//   stores: 4x float4, lane stride 16 B -> full-line segments per instruction
//           (seg0: 1 KiB contiguous; seg1: 2 x 512 B) -> nontemporal-safe.
//   a loads: 4x float4 (rows 2hb-1..2hb+2), lane stride 16 B
//   b loads: 4x float2 (rows 4hb..4hb+3), lane stride 8 B
// b w-halo via lane shuffles; boundary lanes hit first/last predicates
// where the shuffled operand is unselected.
// Output is write-once -> nontemporal stores keep it out of L2/L3 so the
// inputs (100.7 MB) stay L3-resident across replays.

typedef float vfloat4 __attribute__((ext_vector_type(4)));

__device__ __forceinline__ float4 f4_add(float4 p, float4 q) {
    return make_float4(p.x + q.x, p.y + q.y, p.z + q.z, p.w + q.w);
}
__device__ __forceinline__ float4 f4_scale(float4 p, float s) {
    return make_float4(p.x * s, p.y * s, p.z * s, p.w * s);
}

__device__ __forceinline__ void store_nt(float4* p, float4 v) {
    vfloat4 vv;
    vv.x = v.x; vv.y = v.y; vv.z = v.z; vv.w = v.w;
    __builtin_nontemporal_store(vv, reinterpret_cast<vfloat4*>(p));
}

// up_w of one b-row pair: b[2t-1..2t+2] -> outputs w=4t..4t+3
__device__ __forceinline__ float4 upw4(float bm, float2 bq, float bp,
                                       bool first, bool last) {
    constexpr float THIRD = 1.0f / 3.0f;
    float4 r;
    r.x = first ? 0.5f * (bq.x + bq.y) : (bm + bq.x + bq.y) * THIRD;
    r.y = 0.5f * (bq.x + bq.y);
    r.z = last ? 0.5f * (bq.x + bq.y) : (bq.x + bq.y + bp) * THIRD;
    r.w = last ? bq.y : 0.5f * (bq.y + bp);
    return r;
}

template <int Ha, int Wo>
__device__ __forceinline__ void up_combine_body(
    const float* __restrict__ a,   // (N, Ha, Wo)
    const float* __restrict__ b,   // (N, 2*Ha, Wo/2)
    float* __restrict__ out,       // (N, 2*Ha, Wo)
    int lin)
{
    constexpr int H2 = 2 * Ha;
    constexpr int HB = Ha / 2;     // 4-output-row blocks
    constexpr int Wb = Wo / 2;
    constexpr int W4 = Wo / 4;     // float4 per output row
    constexpr int T4 = Wo / 4;     // 4-wide groups per output row
    constexpr float THIRD = 1.0f / 3.0f;

    const int t  = lin % T4;
    const int hb = (lin / T4) % HB;
    const int n  = lin / (T4 * HB);

    // ---------------- a rows: 2hb-1, 2hb, 2hb+1, 2hb+2 (col 4t) ----------
    const float4* a4 = reinterpret_cast<const float4*>(a)
                     + (size_t)n * Ha * W4 + (size_t)(2 * hb) * W4 + t;
    const bool htop = (hb == 0), hbot = (hb == HB - 1);
    float4 a0 = a4[0];            // row 2hb
    float4 a1 = a4[W4];           // row 2hb+1
    float4 am, ap;
    if (!htop) am = a4[-W4];
    if (!hbot) ap = a4[2 * W4];

    // up_h for output rows 4hb..4hb+3
    float4 s01 = f4_add(a0, a1);
    float4 h0 = htop ? f4_scale(s01, 0.5f) : f4_scale(f4_add(am, s01), THIRD);
    float4 h1 = f4_scale(s01, 0.5f);
    float4 h2 = hbot ? f4_scale(s01, 0.5f) : f4_scale(f4_add(s01, ap), THIRD);
    float4 h3 = hbot ? a1 : f4_scale(f4_add(a1, ap), 0.5f);

    // ---------------- b rows: 4hb .. 4hb+3 (cols 2t, 2t+1) ---------------
    const bool first = (t == 0), last = (t == T4 - 1);
    const float* brow = b + ((size_t)n * H2 + (size_t)(4 * hb)) * Wb + 2 * t;
    float2 bq0 = *reinterpret_cast<const float2*>(brow);
    float2 bq1 = *reinterpret_cast<const float2*>(brow + Wb);
    float2 bq2 = *reinterpret_cast<const float2*>(brow + 2 * Wb);
    float2 bq3 = *reinterpret_cast<const float2*>(brow + 3 * Wb);

    float bm0 = __shfl_up(bq0.y, 1), bp0 = __shfl_down(bq0.x, 1);
    float bm1 = __shfl_up(bq1.y, 1), bp1 = __shfl_down(bq1.x, 1);
    float bm2 = __shfl_up(bq2.y, 1), bp2 = __shfl_down(bq2.x, 1);
    float bm3 = __shfl_up(bq3.y, 1), bp3 = __shfl_down(bq3.x, 1);

    float4 w0 = upw4(bm0, bq0, bp0, first, last);
    float4 w1 = upw4(bm1, bq1, bp1, first, last);
    float4 w2 = upw4(bm2, bq2, bp2, first, last);
    float4 w3 = upw4(bm3, bq3, bp3, first, last);

    // ---------------- combine & store (wave-contiguous, nontemporal) -----
    float4* o4 = reinterpret_cast<float4*>(out)
               + ((size_t)n * H2 + (size_t)(4 * hb)) * W4 + t;
    store_nt(o4,          f4_scale(f4_add(h0, w0), 0.5f));
    store_nt(o4 + W4,     f4_scale(f4_add(h1, w1), 0.5f));
    store_nt(o4 + 2 * W4, f4_scale(f4_add(h2, w2), 0.5f));
    store_nt(o4 + 3 * W4, f4_scale(f4_add(h3, w3), 0.5f));
}

__global__ __launch_bounds__(256) void fused_up_kernel(
    const float* __restrict__ x0,
    const float* __restrict__ x1,
    const float* __restrict__ x2,
    float* __restrict__ out0,
    float* __restrict__ out1,
    int g0_blocks)
{
    if (blockIdx.x < (unsigned)g0_blocks) {
        const int lin = blockIdx.x * blockDim.x + threadIdx.x;
        up_combine_body<64, 256>(x0, x1, out0, lin);
    } else {
        const int lin = (blockIdx.x - g0_blocks) * blockDim.x + threadIdx.x;
        up_combine_body<128, 128>(x1, x2, out1, lin);
    }
}

extern "C" void kernel_launch(void* const* d_in, const int* in_sizes, int n_in,
                              void* d_out, int out_size, void* d_ws, size_t ws_size,
                              hipStream_t stream) {
    const float* x0 = (const float*)d_in[0];  // (8,64, 64,256)
    const float* x1 = (const float*)d_in[1];  // (8,64,128,128)
    const float* x2 = (const float*)d_in[2];  // (8,64,256, 64)
    float* out = (float*)d_out;

    const int N = 8 * 64;  // 512
    float* out0 = out;
    float* out1 = out + (size_t)N * 128 * 256;

    // Segment 0: 512 * 32 hb * 64 t = 1,048,576 threads -> 4096 blocks
    // Segment 1: 512 * 64 hb * 32 t = 1,048,576 threads -> 4096 blocks
    const int g0 = (N * (64 / 2) * (256 / 4)) / 256;
    const int g1 = (N * (128 / 2) * (128 / 4)) / 256;
    dim3 grid(g0 + g1), block(256);
    hipLaunchKernelGGL(fused_up_kernel, grid, block, 0, stream,
                       x0, x1, x2, out0, out1, g0);
}

// Round 7
// 44.525 us; speedup vs baseline: 1.5442x; 1.0076x over previous
//
#include <hip/hip_runtime.h>

// Fused anisotropic upsampling:
//   out0 = (up_h(x0) + up_w(x1)) / 2 : (N,128,256), N = 8*64 = 512
//   out1 = (up_h(x1) + up_w(x2)) / 2 : (N,256,128)
// Upsample closed form (L=5, s=2), output length 2W from input length W:
//   j odd , j<=2W-3 : (x[(j-1)/2] + x[(j+1)/2]) / 2
//   j even interior : (x[j/2-1] + x[j/2] + x[j/2+1]) / 3
//   j==0            : (x[0] + x[1]) / 2
//   j==2W-2         : (x[W-2] + x[W-1]) / 2
//   j==2W-1         : x[W-1]
//
// Thread tile: 8 output rows (8hb..8hb+7) x 4 cols (4t..4t+3).
//   a loads: 6x float4  = rows 4hb-1 .. 4hb+4 (halo rows conditional)
//   b loads: 8x float2  = rows 8hb .. 8hb+7, cols 2t..2t+1
//   stores : 8x float4
// All loads/stores are per-instruction wave-contiguous (seg0: 1 KiB/instr,
// seg1: 2 x 512 B/instr) -> full 64 B lines, nontemporal-safe.
// b w-halo via lane shuffles; wave-boundary lanes land on first/last
// predicates where the shuffled operand is unselected.

typedef float vfloat4 __attribute__((ext_vector_type(4)));

__device__ __forceinline__ float4 f4_add(float4 p, float4 q) {
    return make_float4(p.x + q.x, p.y + q.y, p.z + q.z, p.w + q.w);
}
__device__ __forceinline__ float4 f4_scale(float4 p, float s) {
    return make_float4(p.x * s, p.y * s, p.z * s, p.w * s);
}

__device__ __forceinline__ void store_nt(float4* p, float4 v) {
    vfloat4 vv;
    vv.x = v.x; vv.y = v.y; vv.z = v.z; vv.w = v.w;
    __builtin_nontemporal_store(vv, reinterpret_cast<vfloat4*>(p));
}

// up_w of one b-row pair: b[2t-1..2t+2] -> outputs w=4t..4t+3
__device__ __forceinline__ float4 upw4(float bm, float2 bq, float bp,
                                       bool first, bool last) {
    constexpr float THIRD = 1.0f / 3.0f;
    float4 r;
    r.x = first ? 0.5f * (bq.x + bq.y) : (bm + bq.x + bq.y) * THIRD;
    r.y = 0.5f * (bq.x + bq.y);
    r.z = last ? 0.5f * (bq.x + bq.y) : (bq.x + bq.y + bp) * THIRD;
    r.w = last ? bq.y : 0.5f * (bq.y + bp);
    return r;
}

template <int Ha, int Wo>
__device__ __forceinline__ void up_combine_body(
    const float* __restrict__ a,   // (N, Ha, Wo)
    const float* __restrict__ b,   // (N, 2*Ha, Wo/2)
    float* __restrict__ out,       // (N, 2*Ha, Wo)
    int lin)
{
    constexpr int H2  = 2 * Ha;
    constexpr int HB8 = Ha / 4;    // 8-output-row blocks
    constexpr int Wb  = Wo / 2;
    constexpr int W4  = Wo / 4;    // float4 per output row
    constexpr int T4  = Wo / 4;    // 4-wide col groups per row
    constexpr float THIRD = 1.0f / 3.0f;

    const int t  = lin % T4;
    const int hb = (lin / T4) % HB8;
    const int n  = lin / (T4 * HB8);

    const bool htop = (hb == 0), hbot = (hb == HB8 - 1);

    // ---------------- a rows: A[k] = row 4hb-1+k, k=0..5 (col 4t) --------
    const float4* a4 = reinterpret_cast<const float4*>(a)
                     + (size_t)n * Ha * W4 + (size_t)(4 * hb) * W4 + t;
    float4 A0, A1, A2, A3, A4, A5;
    A1 = a4[0];
    A2 = a4[W4];
    A3 = a4[2 * W4];
    A4 = a4[3 * W4];
    if (!htop) A0 = a4[-W4];
    if (!hbot) A5 = a4[4 * W4];

    // ---------------- b rows: 8hb .. 8hb+7 (cols 2t, 2t+1) ---------------
    const bool first = (t == 0), last = (t == T4 - 1);
    const float* brow = b + ((size_t)n * H2 + (size_t)(8 * hb)) * Wb + 2 * t;
    float2 B0 = *reinterpret_cast<const float2*>(brow);
    float2 B1 = *reinterpret_cast<const float2*>(brow + Wb);
    float2 B2 = *reinterpret_cast<const float2*>(brow + 2 * Wb);
    float2 B3 = *reinterpret_cast<const float2*>(brow + 3 * Wb);
    float2 B4 = *reinterpret_cast<const float2*>(brow + 4 * Wb);
    float2 B5 = *reinterpret_cast<const float2*>(brow + 5 * Wb);
    float2 B6 = *reinterpret_cast<const float2*>(brow + 6 * Wb);
    float2 B7 = *reinterpret_cast<const float2*>(brow + 7 * Wb);

    float4* o4 = reinterpret_cast<float4*>(out)
               + ((size_t)n * H2 + (size_t)(8 * hb)) * W4 + t;

    // ---------------- pair p: output rows 8hb+2p, 8hb+2p+1 ---------------
    // even row = (A[p]+A[p+1]+A[p+2])/3   (top: (A1+A2)/2; bottom p=3: (A3+A4)/2)
    // odd  row = (A[p+1]+A[p+2])/2        (bottom p=3: A4)
    {   // p = 0
        float4 s12 = f4_add(A1, A2);
        float4 hev = htop ? f4_scale(s12, 0.5f) : f4_scale(f4_add(A0, s12), THIRD);
        float4 hod = f4_scale(s12, 0.5f);
        float4 wev = upw4(__shfl_up(B0.y, 1), B0, __shfl_down(B0.x, 1), first, last);
        float4 wod = upw4(__shfl_up(B1.y, 1), B1, __shfl_down(B1.x, 1), first, last);
        store_nt(o4,      f4_scale(f4_add(hev, wev), 0.5f));
        store_nt(o4 + W4, f4_scale(f4_add(hod, wod), 0.5f));
    }
    {   // p = 1
        float4 s23 = f4_add(A2, A3);
        float4 hev = f4_scale(f4_add(A1, s23), THIRD);
        float4 hod = f4_scale(s23, 0.5f);
        float4 wev = upw4(__shfl_up(B2.y, 1), B2, __shfl_down(B2.x, 1), first, last);
        float4 wod = upw4(__shfl_up(B3.y, 1), B3, __shfl_down(B3.x, 1), first, last);
        store_nt(o4 + 2 * W4, f4_scale(f4_add(hev, wev), 0.5f));
        store_nt(o4 + 3 * W4, f4_scale(f4_add(hod, wod), 0.5f));
    }
    {   // p = 2
        float4 s34 = f4_add(A3, A4);
        float4 hev = f4_scale(f4_add(A2, s34), THIRD);
        float4 hod = f4_scale(s34, 0.5f);
        float4 wev = upw4(__shfl_up(B4.y, 1), B4, __shfl_down(B4.x, 1), first, last);
        float4 wod = upw4(__shfl_up(B5.y, 1), B5, __shfl_down(B5.x, 1), first, last);
        store_nt(o4 + 4 * W4, f4_scale(f4_add(hev, wev), 0.5f));
        store_nt(o4 + 5 * W4, f4_scale(f4_add(hod, wod), 0.5f));
    }
    {   // p = 3
        float4 s34 = f4_add(A3, A4);
        float4 hev = hbot ? f4_scale(s34, 0.5f) : f4_scale(f4_add(f4_add(A3, A4), A5), THIRD);
        float4 hod = hbot ? A4 : f4_scale(f4_add(A4, A5), 0.5f);
        float4 wev = upw4(__shfl_up(B6.y, 1), B6, __shfl_down(B6.x, 1), first, last);
        float4 wod = upw4(__shfl_up(B7.y, 1), B7, __shfl_down(B7.x, 1), first, last);
        store_nt(o4 + 6 * W4, f4_scale(f4_add(hev, wev), 0.5f));
        store_nt(o4 + 7 * W4, f4_scale(f4_add(hod, wod), 0.5f));
    }
}

__global__ __launch_bounds__(256) void fused_up_kernel(
    const float* __restrict__ x0,
    const float* __restrict__ x1,
    const float* __restrict__ x2,
    float* __restrict__ out0,
    float* __restrict__ out1,
    int g0_blocks)
{
    if (blockIdx.x < (unsigned)g0_blocks) {
        const int lin = blockIdx.x * blockDim.x + threadIdx.x;
        up_combine_body<64, 256>(x0, x1, out0, lin);
    } else {
        const int lin = (blockIdx.x - g0_blocks) * blockDim.x + threadIdx.x;
        up_combine_body<128, 128>(x1, x2, out1, lin);
    }
}

extern "C" void kernel_launch(void* const* d_in, const int* in_sizes, int n_in,
                              void* d_out, int out_size, void* d_ws, size_t ws_size,
                              hipStream_t stream) {
    const float* x0 = (const float*)d_in[0];  // (8,64, 64,256)
    const float* x1 = (const float*)d_in[1];  // (8,64,128,128)
    const float* x2 = (const float*)d_in[2];  // (8,64,256, 64)
    float* out = (float*)d_out;

    const int N = 8 * 64;  // 512
    float* out0 = out;
    float* out1 = out + (size_t)N * 128 * 256;

    // Segment 0: 512 n * 16 hb * 64 t = 524288 threads -> 2048 blocks
    // Segment 1: 512 n * 32 hb * 32 t = 524288 threads -> 2048 blocks
    const int g0 = (N * (64 / 4) * (256 / 4)) / 256;
    const int g1 = (N * (128 / 4) * (128 / 4)) / 256;
    dim3 grid(g0 + g1), block(256);
    hipLaunchKernelGGL(fused_up_kernel, grid, block, 0, stream,
                       x0, x1, x2, out0, out1, g0);
}